// Round 1
// baseline (434.324 us; speedup 1.0000x reference)
//
#include <hip/hip_runtime.h>
#include <math.h>

// Problem constants
#define BN   128    // batch
#define LN   2048   // encoder length
#define HN   256    // hidden
#define EN   256    // embed
#define CHUNKS 8
#define ROWS_PER_CHUNK (LN / CHUNKS)   // 256 rows per chunk, 64 per wave
#define PSTRIDE 260                    // per-(b,chunk) partial: ctx[256], m, s, pad

__device__ __forceinline__ float sigmoidf_(float x) { return 1.0f / (1.0f + __expf(-x)); }
__device__ __forceinline__ float tanhf_(float x)    { return 1.0f - 2.0f / (__expf(2.0f * x) + 1.0f); }

// ---------------------------------------------------------------------------
// K1: one pass over encoder_outputs with online softmax.
// grid (CHUNKS, BN), block 256 (4 waves). Wave w handles 64 consecutive rows.
// Partial per (b,chunk): unnormalized ctx at scale M, plus M and S.
// ---------------------------------------------------------------------------
__global__ __launch_bounds__(256) void attn_partial(
    const float* __restrict__ enc,      // [B][L][H]
    const float* __restrict__ hidden1,  // [B][H]
    float* __restrict__ partials)       // [B][CHUNKS][PSTRIDE]
{
    const int chunk = blockIdx.x;
    const int b     = blockIdx.y;
    const int t     = threadIdx.x;
    const int wave  = t >> 6;
    const int lane  = t & 63;

    __shared__ float lds_ctx[4][256];
    __shared__ float lds_m[4], lds_s[4];

    const float4 h4 = *(const float4*)(hidden1 + b * HN + lane * 4);

    float  m = -INFINITY, s = 0.0f;
    float4 ctx = make_float4(0.f, 0.f, 0.f, 0.f);

    const float* rowp = enc + ((size_t)b * LN + (size_t)chunk * ROWS_PER_CHUNK + wave * 64) * HN + lane * 4;

    #pragma unroll 2
    for (int r = 0; r < 64; ++r) {
        float4 e = *(const float4*)rowp;
        rowp += HN;
        float d = e.x * h4.x + e.y * h4.y + e.z * h4.z + e.w * h4.w;
        #pragma unroll
        for (int off = 32; off > 0; off >>= 1) d += __shfl_xor(d, off, 64);
        // online softmax update
        float mn   = fmaxf(m, d);
        float corr = __expf(m - mn);   // exp(-inf)=0 on first iter
        float p    = __expf(d - mn);
        s = s * corr + p;
        ctx.x = ctx.x * corr + p * e.x;
        ctx.y = ctx.y * corr + p * e.y;
        ctx.z = ctx.z * corr + p * e.z;
        ctx.w = ctx.w * corr + p * e.w;
        m = mn;
    }

    *(float4*)&lds_ctx[wave][lane * 4] = ctx;
    if (lane == 0) { lds_m[wave] = m; lds_s[wave] = s; }
    __syncthreads();

    // combine the 4 waves; thread t == h-index j
    float M = fmaxf(fmaxf(lds_m[0], lds_m[1]), fmaxf(lds_m[2], lds_m[3]));
    float e0 = __expf(lds_m[0] - M), e1 = __expf(lds_m[1] - M);
    float e2 = __expf(lds_m[2] - M), e3 = __expf(lds_m[3] - M);
    float cj = e0 * lds_ctx[0][t] + e1 * lds_ctx[1][t] + e2 * lds_ctx[2][t] + e3 * lds_ctx[3][t];
    float S  = e0 * lds_s[0] + e1 * lds_s[1] + e2 * lds_s[2] + e3 * lds_s[3];

    float* pb = partials + ((size_t)b * CHUNKS + chunk) * PSTRIDE;
    pb[t] = cj;
    if (t == 0) { pb[256] = M; pb[257] = S; }
}

// ---------------------------------------------------------------------------
// K2: merge chunk partials -> context; build xh1 = [ctx | h1_prev] (K=512)
// and xh2 = [embed | (h1 later) | h2_prev] (K=768). grid 128, block 256.
// ---------------------------------------------------------------------------
__global__ __launch_bounds__(256) void combine_prep(
    const float* __restrict__ partials,
    const float* __restrict__ hidden1,
    const float* __restrict__ embed,
    const float* __restrict__ hidden2,
    float* __restrict__ xh1,    // [B][512]
    float* __restrict__ xh2)    // [B][768]
{
    const int b = blockIdx.x;
    const int j = threadIdx.x;
    const float* pb = partials + (size_t)b * CHUNKS * PSTRIDE;

    float mk[CHUNKS], sk[CHUNKS];
    float M = -INFINITY;
    #pragma unroll
    for (int k = 0; k < CHUNKS; ++k) {
        mk[k] = pb[k * PSTRIDE + 256];
        sk[k] = pb[k * PSTRIDE + 257];
        M = fmaxf(M, mk[k]);
    }
    float S = 0.0f, cj = 0.0f;
    #pragma unroll
    for (int k = 0; k < CHUNKS; ++k) {
        float e = __expf(mk[k] - M);
        S  += e * sk[k];
        cj += e * pb[k * PSTRIDE + j];
    }
    cj /= S;

    xh1[b * 512 + j]       = cj;
    xh1[b * 512 + 256 + j] = hidden1[b * HN + j];
    xh2[b * 768 + j]       = embed[b * EN + j];
    xh2[b * 768 + 512 + j] = hidden2[b * HN + j];
}

// ---------------------------------------------------------------------------
// K3: LSTM1. gates[b][g] = xh1[b]·wcat[g] + biases, K=512, then activations.
// grid (32 j-blocks, 8 b-blocks), block 128 = 16 b x 8 j. Weights staged in
// LDS as wq[k][jl][q] (64 KiB) so each thread reads i,f,g,o weights for its
// (j,k) as one aligned ds_read_b128 (conflict-free: 8 jl x b-broadcast).
// ---------------------------------------------------------------------------
__global__ __launch_bounds__(128) void lstm1_kernel(
    const float* __restrict__ xh,     // [B][512]
    const float* __restrict__ w_ih,   // [1024][256]
    const float* __restrict__ w_hh,   // [1024][256]
    const float* __restrict__ b_ih,
    const float* __restrict__ b_hh,
    const float* __restrict__ cell,   // [B][256]
    float* __restrict__ h_out,
    float* __restrict__ c_out,
    float* __restrict__ xh2)          // writes [b][256+j]
{
    __shared__ float wq[512 * 32];    // [k][jl(8)][q(4)] = 64 KiB
    const int t  = threadIdx.x;
    const int jb = blockIdx.x;        // 0..31
    const int bb = blockIdx.y;        // 0..7

    // stage 32 gate rows (8 j x 4 q) x 512 k, coalesced float4 reads
    #pragma unroll 4
    for (int it = 0; it < 32; ++it) {
        int idx  = (it * 128 + t) * 4;      // flat float4 index into [row][512]
        int row  = idx >> 9;
        int k0   = idx & 511;
        int q    = row >> 3, jl = row & 7;
        int g    = q * 256 + jb * 8 + jl;
        float4 v = (k0 < 256) ? *(const float4*)(w_ih + (size_t)g * 256 + k0)
                              : *(const float4*)(w_hh + (size_t)g * 256 + (k0 - 256));
        wq[(k0 + 0) * 32 + jl * 4 + q] = v.x;
        wq[(k0 + 1) * 32 + jl * 4 + q] = v.y;
        wq[(k0 + 2) * 32 + jl * 4 + q] = v.z;
        wq[(k0 + 3) * 32 + jl * 4 + q] = v.w;
    }
    __syncthreads();

    const int jl = t & 7, bl = t >> 3;
    const int b = bb * 16 + bl;
    const int j = jb * 8 + jl;

    float acc0 = 0.f, acc1 = 0.f, acc2 = 0.f, acc3 = 0.f;
    const float* xr = xh + (size_t)b * 512;
    #pragma unroll 4
    for (int k4 = 0; k4 < 128; ++k4) {
        float4 xv = *(const float4*)(xr + k4 * 4);
        #pragma unroll
        for (int i = 0; i < 4; ++i) {
            float xe = (i == 0) ? xv.x : (i == 1) ? xv.y : (i == 2) ? xv.z : xv.w;
            float4 w4 = *(float4*)&wq[(k4 * 4 + i) * 32 + jl * 4];
            acc0 += w4.x * xe; acc1 += w4.y * xe; acc2 += w4.z * xe; acc3 += w4.w * xe;
        }
    }

    float gi = acc0 + b_ih[j]       + b_hh[j];
    float gf = acc1 + b_ih[256 + j] + b_hh[256 + j];
    float gg = acc2 + b_ih[512 + j] + b_hh[512 + j];
    float go = acc3 + b_ih[768 + j] + b_hh[768 + j];

    float cp = cell[b * HN + j];
    float cn = sigmoidf_(gf) * cp + sigmoidf_(gi) * tanhf_(gg);
    float hn = sigmoidf_(go) * tanhf_(cn);

    c_out[b * HN + j] = cn;
    h_out[b * HN + j] = hn;
    xh2[b * 768 + 256 + j] = hn;
}

// ---------------------------------------------------------------------------
// K4: LSTM2. K=768 (w_ih2 over [embed|h1] 512 + w_hh2 over h2_prev 256).
// grid (64 j-blocks, 4 b-blocks), block 128 = 32 b x 4 j. wq = 48 KiB.
// ---------------------------------------------------------------------------
__global__ __launch_bounds__(128) void lstm2_kernel(
    const float* __restrict__ xh,     // [B][768]
    const float* __restrict__ w_ih,   // [1024][512]
    const float* __restrict__ w_hh,   // [1024][256]
    const float* __restrict__ b_ih,
    const float* __restrict__ b_hh,
    const float* __restrict__ cell,   // [B][256]
    float* __restrict__ out0,         // d_out chunk 0 (outputs == h2)
    float* __restrict__ h_out,        // d_out chunk 3
    float* __restrict__ c_out)        // d_out chunk 4
{
    __shared__ float wq[768 * 16];    // [k][jl(4)][q(4)] = 48 KiB
    const int t  = threadIdx.x;
    const int jb = blockIdx.x;        // 0..63
    const int bb = blockIdx.y;        // 0..3

    // stage 16 gate rows x 768 k = 12288 floats; 24 float4 iters of 128 thr
    #pragma unroll 4
    for (int it = 0; it < 24; ++it) {
        int idx = (it * 128 + t) * 4;
        int row = idx / 768;                 // const-div -> magic mul
        int k0  = idx - row * 768;
        int q   = row >> 2, jl = row & 3;
        int g   = q * 256 + jb * 4 + jl;
        float4 v = (k0 < 512) ? *(const float4*)(w_ih + (size_t)g * 512 + k0)
                              : *(const float4*)(w_hh + (size_t)g * 256 + (k0 - 512));
        wq[(k0 + 0) * 16 + jl * 4 + q] = v.x;
        wq[(k0 + 1) * 16 + jl * 4 + q] = v.y;
        wq[(k0 + 2) * 16 + jl * 4 + q] = v.z;
        wq[(k0 + 3) * 16 + jl * 4 + q] = v.w;
    }
    __syncthreads();

    const int jl = t & 3, bl = t >> 2;
    const int b = bb * 32 + bl;
    const int j = jb * 4 + jl;

    float acc0 = 0.f, acc1 = 0.f, acc2 = 0.f, acc3 = 0.f;
    const float* xr = xh + (size_t)b * 768;
    #pragma unroll 4
    for (int k4 = 0; k4 < 192; ++k4) {
        float4 xv = *(const float4*)(xr + k4 * 4);
        #pragma unroll
        for (int i = 0; i < 4; ++i) {
            float xe = (i == 0) ? xv.x : (i == 1) ? xv.y : (i == 2) ? xv.z : xv.w;
            float4 w4 = *(float4*)&wq[(k4 * 4 + i) * 16 + jl * 4];
            acc0 += w4.x * xe; acc1 += w4.y * xe; acc2 += w4.z * xe; acc3 += w4.w * xe;
        }
    }

    float gi = acc0 + b_ih[j]       + b_hh[j];
    float gf = acc1 + b_ih[256 + j] + b_hh[256 + j];
    float gg = acc2 + b_ih[512 + j] + b_hh[512 + j];
    float go = acc3 + b_ih[768 + j] + b_hh[768 + j];

    float cp = cell[b * HN + j];
    float cn = sigmoidf_(gf) * cp + sigmoidf_(gi) * tanhf_(gg);
    float hn = sigmoidf_(go) * tanhf_(cn);

    out0[b * HN + j]  = hn;   // outputs chunk (== h2)
    h_out[b * HN + j] = hn;   // h2 chunk
    c_out[b * HN + j] = cn;   // c2 chunk
}

// ---------------------------------------------------------------------------
extern "C" void kernel_launch(void* const* d_in, const int* in_sizes, int n_in,
                              void* d_out, int out_size, void* d_ws, size_t ws_size,
                              hipStream_t stream)
{
    const float* embed   = (const float*)d_in[0];   // (B,1,E)
    const float* enc     = (const float*)d_in[1];   // (B,L,H)
    const float* hidden1 = (const float*)d_in[2];   // (1,B,H)
    const float* cell1   = (const float*)d_in[3];
    const float* hidden2 = (const float*)d_in[4];
    const float* cell2   = (const float*)d_in[5];
    const float* w_ih1   = (const float*)d_in[6];   // (1024,256)
    const float* w_hh1   = (const float*)d_in[7];   // (1024,256)
    const float* b_ih1   = (const float*)d_in[8];
    const float* b_hh1   = (const float*)d_in[9];
    const float* w_ih2   = (const float*)d_in[10];  // (1024,512)
    const float* w_hh2   = (const float*)d_in[11];  // (1024,256)
    const float* b_ih2   = (const float*)d_in[12];
    const float* b_hh2   = (const float*)d_in[13];

    float* out = (float*)d_out;
    // out layout: [0) outputs(h2) 32768 | 32768) h1 | 65536) c1 | 98304) h2 | 131072) c2
    float* ws = (float*)d_ws;
    float* partials = ws;                                  // 128*8*260 = 266240 floats
    float* xh1 = ws + (size_t)BN * CHUNKS * PSTRIDE;       // 128*512
    float* xh2 = xh1 + (size_t)BN * 512;                   // 128*768

    attn_partial<<<dim3(CHUNKS, BN), 256, 0, stream>>>(enc, hidden1, partials);
    combine_prep<<<dim3(BN), 256, 0, stream>>>(partials, hidden1, embed, hidden2, xh1, xh2);
    lstm1_kernel<<<dim3(32, 8), 128, 0, stream>>>(xh1, w_ih1, w_hh1, b_ih1, b_hh1, cell1,
                                                  out + 32768, out + 65536, xh2);
    lstm2_kernel<<<dim3(64, 4), 128, 0, stream>>>(xh2, w_ih2, w_hh2, b_ih2, b_hh2, cell2,
                                                  out, out + 98304, out + 131072);
}